// Round 1
// baseline (296.623 us; speedup 1.0000x reference)
//
#include <hip/hip_runtime.h>
#include <math.h>

typedef __attribute__((ext_vector_type(8)))  short  short8;
typedef __attribute__((ext_vector_type(16))) float  float16;

#define TWO_PI_OVER_32 0.19634954084936207f

static __device__ __forceinline__ unsigned short f2bf(float f) {
    unsigned int u = __float_as_uint(f);
    u = (u + 0x7FFFu + ((u >> 16) & 1u)) >> 16;
    return (unsigned short)u;
}

// ---------------------------------------------------------------------------
// K0: weight (co,ci,3,3) fp32 -> wt bf16, layout [t][ci>>3][co][ci&7]
// ---------------------------------------------------------------------------
__global__ __launch_bounds__(256) void k_wt(const float* __restrict__ w,
                                            unsigned short* __restrict__ wt) {
    int tid = blockIdx.x * 256 + threadIdx.x;      // 65536 threads
    int co = tid >> 8, ci = tid & 255;
    const float* src = w + (co * 256 + ci) * 9;
    int base = (ci >> 3) * 2048 + co * 8 + (ci & 7);
    #pragma unroll
    for (int t = 0; t < 9; ++t)
        wt[t * 65536 + base] = f2bf(src[t]);
}

// ---------------------------------------------------------------------------
// K1: conv y = circular-corr(x, w) + bias   via implicit GEMM, 32x32x16 MFMA
// grid (8 row-tiles, 2 co-tiles, 32 batch), block 256 (4 waves in 2x2)
// ---------------------------------------------------------------------------
__global__ __launch_bounds__(256) void k_conv(const float* __restrict__ x,
                                              const unsigned short* __restrict__ wt,
                                              const float* __restrict__ bias,
                                              float* __restrict__ y) {
    // xs: [row 6][cig 2][col 34][8 ci]  bf16 (halo tile, ci contiguous per lane)
    // ws: [t 9][cig 2][co 128][8 ci]    bf16
    __shared__ unsigned short xs[6 * 2 * 34 * 8];   // 6528 B
    __shared__ unsigned short wsm[9 * 2 * 128 * 8]; // 36864 B

    const int tid  = threadIdx.x;
    const int lane = tid & 63;
    const int wave = tid >> 6;
    const int wm = wave >> 1, wn = wave & 1;
    const int half = lane >> 5;
    const int m = lane & 31;

    const int r0  = blockIdx.x * 4;
    const int co0 = blockIdx.y * 128;
    const int b   = blockIdx.z;

    float16 acc[2][2];
    #pragma unroll
    for (int i = 0; i < 2; ++i)
        #pragma unroll
        for (int j = 0; j < 2; ++j)
            #pragma unroll
            for (int r = 0; r < 16; ++r) acc[i][j][r] = 0.f;

    const int at9[9] = {0,0,0,1,1,1,2,2,2};
    const int bt9[9] = {0,1,2,0,1,2,0,1,2};

    for (int kc = 0; kc < 16; ++kc) {
        // ---- stage weights: 2304 x 16B granules ----
        {
            const uint4* wtv = (const uint4*)wt;
            uint4* wsv = (uint4*)wsm;
            #pragma unroll
            for (int it = 0; it < 9; ++it) {
                int i = tid + it * 256;             // i < 2304 always
                int co  = i & 127;
                int cig = (i >> 7) & 1;
                int t   = i >> 8;
                wsv[(t * 2 + cig) * 128 + co] =
                    wtv[t * 8192 + (2 * kc + cig) * 256 + (co0 + co)];
            }
        }
        // ---- stage x halo tile: 6 rows x 34 cols x 16 ci (as bf16 pairs) ----
        {
            unsigned int* xsu = (unsigned int*)xs;
            for (int i = tid; i < 6 * 34 * 8; i += 256) {
                int col  = i % 34;
                int rest = i / 34;
                int row  = rest % 6;
                int cip  = rest / 6;                 // 0..7 (pair of ci)
                int ci   = kc * 16 + cip * 2;
                int gr = (r0 + row + 31) & 31;
                int gc = (col + 31) & 31;
                const float* xp = x + ((b * 256 + ci) * 32 + gr) * 32 + gc;
                unsigned int lo = f2bf(xp[0]);
                unsigned int hi = f2bf(xp[1024]);
                xsu[((row * 2 + (cip >> 2)) * 34 + col) * 4 + (cip & 3)] =
                    (hi << 16) | lo;
            }
        }
        __syncthreads();

        const short8* wsl = (const short8*)wsm;
        const short8* xsl = (const short8*)xs;
        for (int t = 0; t < 9; ++t) {
            const int atv = at9[t], btv = bt9[t];
            short8 a0 = wsl[(t * 2 + half) * 128 + (wm * 64 + m)];
            short8 a1 = wsl[(t * 2 + half) * 128 + (wm * 64 + 32 + m)];
            #pragma unroll
            for (int ns = 0; ns < 2; ++ns) {
                int rowh = wn * 2 + ns + atv;        // 0..5
                short8 bf = xsl[(rowh * 2 + half) * 34 + m + btv];
                acc[0][ns] = __builtin_amdgcn_mfma_f32_32x32x16_bf16(a0, bf, acc[0][ns], 0, 0, 0);
                acc[1][ns] = __builtin_amdgcn_mfma_f32_32x32x16_bf16(a1, bf, acc[1][ns], 0, 0, 0);
            }
        }
        __syncthreads();
    }

    // ---- epilogue: C layout (32x32): col=lane&31, row=(reg&3)+8*(reg>>2)+4*half
    const int j = lane & 31;
    #pragma unroll
    for (int ms = 0; ms < 2; ++ms) {
        int cobase = co0 + wm * 64 + ms * 32;
        #pragma unroll
        for (int ns = 0; ns < 2; ++ns) {
            int r = r0 + wn * 2 + ns;
            #pragma unroll
            for (int reg = 0; reg < 16; ++reg) {
                int crow = (reg & 3) + 8 * (reg >> 2) + 4 * half;
                int co = cobase + crow;
                y[(b * 256 + co) * 1024 + r * 32 + j] = acc[ms][ns][reg] + bias[co];
            }
        }
    }
}

// ---------------------------------------------------------------------------
// K2: tap-correlation matrices
//   D_row[p][45] = sum_c w[p,c,ta]*w[p,c,tb]   (ta<=tb packed)
//   D_col[c][45] = sum_p w[p,c,ta]*w[p,c,tb]
// grid 512: blocks 0..255 row mode (p=blk), 256..511 col mode (c=blk-256)
// ---------------------------------------------------------------------------
__global__ __launch_bounds__(256) void k_dmat(const float* __restrict__ w,
                                              float* __restrict__ Drow,
                                              float* __restrict__ Dcol) {
    bool colmode = blockIdx.x >= 256;
    int pc = blockIdx.x & 255;
    __shared__ float sdata[45];
    int tid = threadIdx.x;
    int lane = tid & 63;
    if (tid < 45) sdata[tid] = 0.f;
    __syncthreads();

    int p = colmode ? tid : pc;
    int c = colmode ? pc : tid;
    float w9[9];
    #pragma unroll
    for (int t = 0; t < 9; ++t) w9[t] = w[(p * 256 + c) * 9 + t];

    int idx = 0;
    for (int ta = 0; ta < 9; ++ta)
        for (int tb = ta; tb < 9; ++tb) {
            float v = w9[ta] * w9[tb];
            #pragma unroll
            for (int off = 32; off > 0; off >>= 1) v += __shfl_down(v, off);
            if (lane == 0) atomicAdd(&sdata[idx], v);
            ++idx;
        }
    __syncthreads();
    float* D = colmode ? Dcol : Drow;
    if (tid < 45) D[pc * 45 + tid] = sdata[tid];
}

// ---------------------------------------------------------------------------
// K3: Row/Col loss: per bin n=(u,v): RowNorm^2[p] = sum coef[tt']*D_row[p][tt']
// accumulate (sqrt(.)-1)^2 into accum[0] (row) / accum[1] (col)
// ---------------------------------------------------------------------------
__global__ __launch_bounds__(256) void k_rowcol(const float* __restrict__ Drow,
                                                const float* __restrict__ Dcol,
                                                float* __restrict__ accum) {
    int bin = blockIdx.x;          // 0..543
    int u = bin / 17, v = bin % 17;
    __shared__ float coef[45];
    __shared__ float red[2];
    int tid = threadIdx.x;
    if (tid < 2) red[tid] = 0.f;
    if (tid < 45) {
        int idx = 0, TA = 0, TB = 0;
        for (int ta = 0; ta < 9; ++ta)
            for (int tb = ta; tb < 9; ++tb) {
                if (idx == tid) { TA = ta; TB = tb; }
                ++idx;
            }
        int da = TA / 3 - TB / 3;
        int db = TA % 3 - TB % 3;
        float cth = cosf(TWO_PI_OVER_32 * (float)(u * da + v * db));
        coef[tid] = (TA == TB) ? 1.f : 2.f * cth;
    }
    __syncthreads();

    float s1 = 0.f, s2 = 0.f;
    const float* dr = Drow + tid * 45;
    const float* dc = Dcol + tid * 45;
    #pragma unroll
    for (int i = 0; i < 45; ++i) {
        s1 += coef[i] * dr[i];
        s2 += coef[i] * dc[i];
    }
    float e1 = sqrtf(fmaxf(s1, 0.f)) - 1.f; e1 *= e1;
    float e2 = sqrtf(fmaxf(s2, 0.f)) - 1.f; e2 *= e2;
    #pragma unroll
    for (int off = 32; off > 0; off >>= 1) {
        e1 += __shfl_down(e1, off);
        e2 += __shfl_down(e2, off);
    }
    if ((tid & 63) == 0) { atomicAdd(&red[0], e1); atomicAdd(&red[1], e2); }
    __syncthreads();
    if (tid == 0) { atomicAdd(&accum[0], red[0]); atomicAdd(&accum[1], red[1]); }
}

// ---------------------------------------------------------------------------
// K4: AngLoss. Block p, thread q (q>p):
//   c[t][t'] = sum_ci w[p,ci,t]*w[q,ci,t']
//   g[da][db] = sum over (t,t') with tap-delta (da,db)
//   S_pq = 32 * sum_da sum_{db,db'} g*g*ReS(|db-db'|),  ReS(d)=sum_{v=0..16}cos(2πvd/32)
// (equals sum over all 544 rfft bins of |HHT[n,p,q]|^2; shift/conj cancel)
// ---------------------------------------------------------------------------
__global__ __launch_bounds__(256) void k_ang(const float* __restrict__ w,
                                             float* __restrict__ accum) {
    int p = blockIdx.x;            // 0..255
    int q = threadIdx.x;
    __shared__ float wp[2304];
    __shared__ float red;
    if (threadIdx.x == 0) red = 0.f;
    for (int i = threadIdx.x; i < 2304; i += 256) wp[i] = w[p * 2304 + i];
    __syncthreads();

    float S = 0.f;
    if (q > p) {
        float c[9][9];
        #pragma unroll
        for (int i = 0; i < 9; ++i)
            #pragma unroll
            for (int jj = 0; jj < 9; ++jj) c[i][jj] = 0.f;

        const float* wq = w + q * 2304;
        for (int ci = 0; ci < 256; ++ci) {
            float a[9], bq[9];
            #pragma unroll
            for (int t = 0; t < 9; ++t) a[t] = wp[ci * 9 + t];
            #pragma unroll
            for (int t = 0; t < 9; ++t) bq[t] = wq[ci * 9 + t];
            #pragma unroll
            for (int ta = 0; ta < 9; ++ta)
                #pragma unroll
                for (int tb = 0; tb < 9; ++tb)
                    c[ta][tb] += a[ta] * bq[tb];
        }

        float g[5][5];
        #pragma unroll
        for (int i = 0; i < 5; ++i)
            #pragma unroll
            for (int jj = 0; jj < 5; ++jj) g[i][jj] = 0.f;
        #pragma unroll
        for (int ta = 0; ta < 9; ++ta)
            #pragma unroll
            for (int tb = 0; tb < 9; ++tb)
                g[ta / 3 - tb / 3 + 2][ta % 3 - tb % 3 + 2] += c[ta][tb];

        float ReS[5];
        #pragma unroll
        for (int d = 0; d < 5; ++d) {
            float s = 0.f;
            for (int vv = 0; vv < 17; ++vv)
                s += cosf(TWO_PI_OVER_32 * (float)(vv * d));
            ReS[d] = s;
        }
        #pragma unroll
        for (int da = 0; da < 5; ++da)
            #pragma unroll
            for (int d1 = 0; d1 < 5; ++d1)
                #pragma unroll
                for (int d2 = 0; d2 < 5; ++d2) {
                    int dd = d1 - d2; if (dd < 0) dd = -dd;
                    S += g[da][d1] * g[da][d2] * ReS[dd];
                }
        S *= 32.f;
    }
    #pragma unroll
    for (int off = 32; off > 0; off >>= 1) S += __shfl_down(S, off);
    if ((threadIdx.x & 63) == 0) atomicAdd(&red, S);
    __syncthreads();
    if (threadIdx.x == 0) atomicAdd(&accum[2], red);
}

// ---------------------------------------------------------------------------
// K5: finalize L = 256*ColLoss + 256*RowLoss + AngLoss
// ---------------------------------------------------------------------------
__global__ void k_fin(const float* __restrict__ accum, float* __restrict__ out) {
    if (threadIdx.x == 0 && blockIdx.x == 0) {
        float row = accum[0], col = accum[1], ang = accum[2];
        // 256*RowLoss = 256*row/(544*256) = row/544 ; same for col
        out[8388608] = row / 544.f + col / 544.f + ang / (544.f * 32640.f);
    }
}

// ---------------------------------------------------------------------------
extern "C" void kernel_launch(void* const* d_in, const int* in_sizes, int n_in,
                              void* d_out, int out_size, void* d_ws, size_t ws_size,
                              hipStream_t stream) {
    const float* x    = (const float*)d_in[0];   // (32,256,32,32)
    const float* w    = (const float*)d_in[1];   // (256,256,3,3)
    const float* bias = (const float*)d_in[2];   // (256,)
    float* out = (float*)d_out;

    char* ws = (char*)d_ws;
    unsigned short* wt = (unsigned short*)ws;            // 1,179,648 B
    float* Drow  = (float*)(ws + 1179648);               //    46,080 B
    float* Dcol  = (float*)(ws + 1225728);               //    46,080 B
    float* accum = (float*)(ws + 1271808);               //        16 B

    hipMemsetAsync(accum, 0, 16, stream);

    k_wt    <<<256, 256, 0, stream>>>(w, wt);
    k_conv  <<<dim3(8, 2, 32), 256, 0, stream>>>(x, wt, bias, out);
    k_dmat  <<<512, 256, 0, stream>>>(w, Drow, Dcol);
    k_rowcol<<<544, 256, 0, stream>>>(Drow, Dcol, accum);
    k_ang   <<<256, 256, 0, stream>>>(w, accum);
    k_fin   <<<1, 64, 0, stream>>>(accum, out);
}

// Round 2
// 220.706 us; speedup vs baseline: 1.3440x; 1.3440x over previous
//
#include <hip/hip_runtime.h>
#include <math.h>

typedef __attribute__((ext_vector_type(8)))  short  short8;
typedef __attribute__((ext_vector_type(16))) float  float16;

#define TWO_PI_OVER_32 0.19634954084936207f

static __device__ __forceinline__ unsigned short f2bf(float f) {
    unsigned int u = __float_as_uint(f);
    u = (u + 0x7FFFu + ((u >> 16) & 1u)) >> 16;
    return (unsigned short)u;
}
static __device__ __forceinline__ float bf2f(unsigned short s) {
    return __uint_as_float(((unsigned int)s) << 16);
}

// ---------------------------------------------------------------------------
// K0: weight (co,ci,3,3) fp32 -> wt bf16, granule layout [t][ci>>3][co][ci&7]
// ---------------------------------------------------------------------------
__global__ __launch_bounds__(256) void k_wt(const float* __restrict__ w,
                                            unsigned short* __restrict__ wt) {
    int tid = blockIdx.x * 256 + threadIdx.x;      // 65536 threads
    int co = tid >> 8, ci = tid & 255;
    const float* src = w + (co * 256 + ci) * 9;
    int base = (ci >> 3) * 2048 + co * 8 + (ci & 7);
    #pragma unroll
    for (int t = 0; t < 9; ++t)
        wt[t * 65536 + base] = f2bf(src[t]);
}

// ---------------------------------------------------------------------------
// K0b: x fp32 (b,ci,r,c) -> xb bf16 granules [b][ci>>3][r][c][ci&7]
// ---------------------------------------------------------------------------
__global__ __launch_bounds__(256) void k_xcvt(const float* __restrict__ x,
                                              unsigned short* __restrict__ xb) {
    int g = blockIdx.x * 256 + threadIdx.x;        // 1,048,576 granules
    int c = g & 31, r = (g >> 5) & 31, cig = (g >> 10) & 31, b = g >> 15;
    const float* xp = x + ((b * 256 + cig * 8) * 32 + r) * 32 + c;
    union { unsigned short u[8]; uint4 v; } pk;
    #pragma unroll
    for (int u = 0; u < 8; ++u) pk.u[u] = f2bf(xp[u * 1024]);
    ((uint4*)xb)[g] = pk.v;
}

// ---------------------------------------------------------------------------
// K1: conv y = circular-corr(x,w)+bias. Implicit GEMM, dual-path operands:
//   A (weights) direct from L2 global; B (x) via 10 KB LDS tile.
// block 128 thr (2 waves), wave tile M=64co x N=128 (4 rows x 32 cols)
// grid (4 co-tiles, 4 row-tiles, 32 batch) = 512 blocks
// ---------------------------------------------------------------------------
__global__ __launch_bounds__(128, 2) void k_conv(const unsigned short* __restrict__ xb,
                                                 const unsigned short* __restrict__ wt,
                                                 const float* __restrict__ bias,
                                                 float* __restrict__ y) {
    __shared__ unsigned short xs[640 * 8];     // [slot 10][cig 2][col 32][8ci], 10240 B

    const int tid  = threadIdx.x;
    const int lane = tid & 63;
    const int wn   = tid >> 6;                 // wave -> row-half
    const int half = lane >> 5;
    const int m    = lane & 31;

    const int co0 = blockIdx.x * 64;
    const int r0  = blockIdx.y * 8;
    const int b   = blockIdx.z;

    float16 acc[2][4];
    #pragma unroll
    for (int i = 0; i < 2; ++i)
        #pragma unroll
        for (int ns = 0; ns < 4; ++ns)
            #pragma unroll
            for (int r = 0; r < 16; ++r) acc[i][ns][r] = 0.f;

    const uint4*  xbv = (const uint4*)xb;
    uint4*        xsv = (uint4*)xs;
    const short8* xsl = (const short8*)xs;
    const short8* wtl = (const short8*)wt;

    for (int kc = 0; kc < 16; ++kc) {
        // stage x tile: 640 granules, 5 per thread, wrap handled in gr
        #pragma unroll
        for (int gg = 0; gg < 5; ++gg) {
            int i   = tid + gg * 128;
            int col = i & 31, cig = (i >> 5) & 1, slot = i >> 6;
            int gr  = (r0 + slot + 31) & 31;
            xsv[i] = xbv[((b * 32 + kc * 2 + cig) * 32 + gr) * 32 + col];
        }
        __syncthreads();

        #pragma unroll
        for (int t = 0; t < 9; ++t) {
            const int atv = t / 3, btv = t % 3;
            int wg = (t * 32 + kc * 2 + half) * 256 + co0 + m;
            short8 a0 = wtl[wg];
            short8 a1 = wtl[wg + 32];
            #pragma unroll
            for (int ns = 0; ns < 4; ++ns) {
                int slot = wn * 4 + ns + atv;          // 0..9
                short8 bf = xsl[(slot * 2 + half) * 32 + ((m + btv + 31) & 31)];
                acc[0][ns] = __builtin_amdgcn_mfma_f32_32x32x16_bf16(a0, bf, acc[0][ns], 0, 0, 0);
                acc[1][ns] = __builtin_amdgcn_mfma_f32_32x32x16_bf16(a1, bf, acc[1][ns], 0, 0, 0);
            }
        }
        __syncthreads();
    }

    // epilogue: C layout: col=lane&31, row=(reg&3)+8*(reg>>2)+4*half
    #pragma unroll
    for (int i = 0; i < 2; ++i) {
        #pragma unroll
        for (int ns = 0; ns < 4; ++ns) {
            int r = r0 + wn * 4 + ns;
            #pragma unroll
            for (int reg = 0; reg < 16; ++reg) {
                int crow = (reg & 3) + 8 * (reg >> 2) + 4 * half;
                int co = co0 + i * 32 + crow;
                y[(b * 256 + co) * 1024 + r * 32 + m] = acc[i][ns][reg] + bias[co];
            }
        }
    }
}

// ---------------------------------------------------------------------------
// K2: tap-correlation matrices (exact fp32, for Row/Col losses)
// ---------------------------------------------------------------------------
__global__ __launch_bounds__(256) void k_dmat(const float* __restrict__ w,
                                              float* __restrict__ Drow,
                                              float* __restrict__ Dcol) {
    bool colmode = blockIdx.x >= 256;
    int pc = blockIdx.x & 255;
    __shared__ float sdata[45];
    int tid = threadIdx.x;
    int lane = tid & 63;
    if (tid < 45) sdata[tid] = 0.f;
    __syncthreads();

    int p = colmode ? tid : pc;
    int c = colmode ? pc : tid;
    float w9[9];
    #pragma unroll
    for (int t = 0; t < 9; ++t) w9[t] = w[(p * 256 + c) * 9 + t];

    int idx = 0;
    for (int ta = 0; ta < 9; ++ta)
        for (int tb = ta; tb < 9; ++tb) {
            float v = w9[ta] * w9[tb];
            #pragma unroll
            for (int off = 32; off > 0; off >>= 1) v += __shfl_down(v, off);
            if (lane == 0) atomicAdd(&sdata[idx], v);
            ++idx;
        }
    __syncthreads();
    float* D = colmode ? Dcol : Drow;
    if (tid < 45) D[pc * 45 + tid] = sdata[tid];
}

// ---------------------------------------------------------------------------
// K3: Row/Col loss accumulation per bin
// ---------------------------------------------------------------------------
__global__ __launch_bounds__(256) void k_rowcol(const float* __restrict__ Drow,
                                                const float* __restrict__ Dcol,
                                                float* __restrict__ accum) {
    int bin = blockIdx.x;          // 0..543
    int u = bin / 17, v = bin % 17;
    __shared__ float coef[45];
    __shared__ float red[2];
    int tid = threadIdx.x;
    if (tid < 2) red[tid] = 0.f;
    if (tid < 45) {
        int idx = 0, TA = 0, TB = 0;
        for (int ta = 0; ta < 9; ++ta)
            for (int tb = ta; tb < 9; ++tb) {
                if (idx == tid) { TA = ta; TB = tb; }
                ++idx;
            }
        int da = TA / 3 - TB / 3;
        int db = TA % 3 - TB % 3;
        float cth = cosf(TWO_PI_OVER_32 * (float)(u * da + v * db));
        coef[tid] = (TA == TB) ? 1.f : 2.f * cth;
    }
    __syncthreads();

    float s1 = 0.f, s2 = 0.f;
    const float* dr = Drow + tid * 45;
    const float* dc = Dcol + tid * 45;
    #pragma unroll
    for (int i = 0; i < 45; ++i) {
        s1 += coef[i] * dr[i];
        s2 += coef[i] * dc[i];
    }
    float e1 = sqrtf(fmaxf(s1, 0.f)) - 1.f; e1 *= e1;
    float e2 = sqrtf(fmaxf(s2, 0.f)) - 1.f; e2 *= e2;
    #pragma unroll
    for (int off = 32; off > 0; off >>= 1) {
        e1 += __shfl_down(e1, off);
        e2 += __shfl_down(e2, off);
    }
    if ((tid & 63) == 0) { atomicAdd(&red[0], e1); atomicAdd(&red[1], e2); }
    __syncthreads();
    if (tid == 0) { atomicAdd(&accum[0], red[0]); atomicAdd(&accum[1], red[1]); }
}

// ---------------------------------------------------------------------------
// K4a: V prep: Vb[p*10+ta][ci] bf16 (tap slot 9 zeroed), granules [row][ci>>3]
// ---------------------------------------------------------------------------
__global__ __launch_bounds__(256) void k_vprep(const float* __restrict__ w,
                                               unsigned short* __restrict__ Vb) {
    int g = blockIdx.x * 256 + threadIdx.x;   // 81920 granules
    int cigg = g & 31, row = g >> 5;
    int p = row / 10, ta = row % 10;
    union { unsigned short u[8]; uint4 v; } pk;
    if (ta < 9) {
        #pragma unroll
        for (int u = 0; u < 8; ++u)
            pk.u[u] = f2bf(w[(p * 256 + cigg * 8 + u) * 9 + ta]);
    } else {
        #pragma unroll
        for (int u = 0; u < 8; ++u) pk.u[u] = 0;
    }
    ((uint4*)Vb)[g] = pk.v;
}

// ---------------------------------------------------------------------------
// K4b: Gram G = V V^T (2560x2560, K=256) bf16 MFMA, upper-triangle tiles only.
// grid 210 blocks (20x20 triangular), 4 waves 2x2, wave 64x64, no LDS.
// ---------------------------------------------------------------------------
__global__ __launch_bounds__(256) void k_gram(const unsigned short* __restrict__ Vb,
                                              unsigned short* __restrict__ Gb) {
    int blk = blockIdx.x, I = 0;
    while (blk >= 20 - I) { blk -= 20 - I; ++I; }
    int J = I + blk;

    const int tid  = threadIdx.x;
    const int lane = tid & 63;
    const int wave = tid >> 6;
    const int wm = wave >> 1, wn = wave & 1;
    const int half = lane >> 5;
    const int m = lane & 31;

    const int row0 = I * 128 + wm * 64;
    const int col0 = J * 128 + wn * 64;

    float16 acc[2][2];
    #pragma unroll
    for (int i = 0; i < 2; ++i)
        #pragma unroll
        for (int j = 0; j < 2; ++j)
            #pragma unroll
            for (int r = 0; r < 16; ++r) acc[i][j][r] = 0.f;

    const short8* vb = (const short8*)Vb;
    for (int kc = 0; kc < 16; ++kc) {
        int cig = kc * 2 + half;
        short8 a0 = vb[(row0 + m) * 32 + cig];
        short8 a1 = vb[(row0 + 32 + m) * 32 + cig];
        short8 b0 = vb[(col0 + m) * 32 + cig];
        short8 b1 = vb[(col0 + 32 + m) * 32 + cig];
        acc[0][0] = __builtin_amdgcn_mfma_f32_32x32x16_bf16(a0, b0, acc[0][0], 0, 0, 0);
        acc[0][1] = __builtin_amdgcn_mfma_f32_32x32x16_bf16(a0, b1, acc[0][1], 0, 0, 0);
        acc[1][0] = __builtin_amdgcn_mfma_f32_32x32x16_bf16(a1, b0, acc[1][0], 0, 0, 0);
        acc[1][1] = __builtin_amdgcn_mfma_f32_32x32x16_bf16(a1, b1, acc[1][1], 0, 0, 0);
    }
    #pragma unroll
    for (int i = 0; i < 2; ++i)
        #pragma unroll
        for (int j = 0; j < 2; ++j)
            #pragma unroll
            for (int reg = 0; reg < 16; ++reg) {
                int crow = (reg & 3) + 8 * (reg >> 2) + 4 * half;
                Gb[(row0 + i * 32 + crow) * 2560 + col0 + j * 32 + m] =
                    f2bf(acc[i][j][reg]);
            }
}

// ---------------------------------------------------------------------------
// K4c: AngLoss reduction. Block p stages G rows p*10+ta (9x2560 bf16) in LDS;
// thread q>p builds delta-grouped g[5][5] and closed-form bin sum.
// ---------------------------------------------------------------------------
__global__ __launch_bounds__(256) void k_angred(const unsigned short* __restrict__ Gb,
                                                float* __restrict__ accum) {
    int p = blockIdx.x;
    __shared__ unsigned short gs[9 * 2560];    // 46080 B
    __shared__ float red;
    if (threadIdx.x == 0) red = 0.f;
    uint4* gsv = (uint4*)gs;
    const uint4* gbv = (const uint4*)Gb;
    for (int i = threadIdx.x; i < 2880; i += 256) {
        int rr = i / 320, cc = i - rr * 320;
        gsv[i] = gbv[(p * 10 + rr) * 320 + cc];
    }
    __syncthreads();

    int q = threadIdx.x;
    float S = 0.f;
    if (q > p) {
        float g5[5][5];
        #pragma unroll
        for (int i = 0; i < 5; ++i)
            #pragma unroll
            for (int j = 0; j < 5; ++j) g5[i][j] = 0.f;
        #pragma unroll
        for (int ta = 0; ta < 9; ++ta)
            #pragma unroll
            for (int tb = 0; tb < 9; ++tb) {
                float c = bf2f(gs[ta * 2560 + q * 10 + tb]);
                g5[ta / 3 - tb / 3 + 2][ta % 3 - tb % 3 + 2] += c;
            }
        float ReS[5];
        #pragma unroll
        for (int d = 0; d < 5; ++d) {
            float s = 0.f;
            for (int vv = 0; vv < 17; ++vv)
                s += cosf(TWO_PI_OVER_32 * (float)(vv * d));
            ReS[d] = s;
        }
        #pragma unroll
        for (int da = 0; da < 5; ++da)
            #pragma unroll
            for (int d1 = 0; d1 < 5; ++d1)
                #pragma unroll
                for (int d2 = 0; d2 < 5; ++d2) {
                    int dd = d1 - d2; if (dd < 0) dd = -dd;
                    S += g5[da][d1] * g5[da][d2] * ReS[dd];
                }
        S *= 32.f;
    }
    #pragma unroll
    for (int off = 32; off > 0; off >>= 1) S += __shfl_down(S, off);
    if ((threadIdx.x & 63) == 0) atomicAdd(&red, S);
    __syncthreads();
    if (threadIdx.x == 0) atomicAdd(&accum[2], red);
}

// ---------------------------------------------------------------------------
// K5: finalize L
// ---------------------------------------------------------------------------
__global__ void k_fin(const float* __restrict__ accum, float* __restrict__ out) {
    if (threadIdx.x == 0 && blockIdx.x == 0) {
        float row = accum[0], col = accum[1], ang = accum[2];
        out[8388608] = row / 544.f + col / 544.f + ang / (544.f * 32640.f);
    }
}

// ---------------------------------------------------------------------------
extern "C" void kernel_launch(void* const* d_in, const int* in_sizes, int n_in,
                              void* d_out, int out_size, void* d_ws, size_t ws_size,
                              hipStream_t stream) {
    const float* x    = (const float*)d_in[0];   // (32,256,32,32)
    const float* w    = (const float*)d_in[1];   // (256,256,3,3)
    const float* bias = (const float*)d_in[2];   // (256,)
    float* out = (float*)d_out;

    char* ws = (char*)d_ws;
    unsigned short* wt = (unsigned short*)ws;               //  1,179,648 B
    unsigned short* xb = (unsigned short*)(ws + 1179648);   // 16,777,216 B
    unsigned short* Gb = xb;                                // aliases xb (after conv)
    unsigned short* Vb = (unsigned short*)(ws + 17956864);  //  1,310,720 B
    float* Drow  = (float*)(ws + 19267584);                 //     46,080 B
    float* Dcol  = (float*)(ws + 19313664);                 //     46,080 B
    float* accum = (float*)(ws + 19359744);                 //         16 B

    hipMemsetAsync(accum, 0, 16, stream);

    k_wt    <<<256, 256, 0, stream>>>(w, wt);
    k_xcvt  <<<4096, 256, 0, stream>>>(x, xb);
    k_conv  <<<dim3(4, 4, 32), 128, 0, stream>>>(xb, wt, bias, out);
    k_vprep <<<320, 256, 0, stream>>>(w, Vb);
    k_gram  <<<210, 256, 0, stream>>>(Vb, Gb);              // Gb overwrites xb region
    k_dmat  <<<512, 256, 0, stream>>>(w, Drow, Dcol);
    k_rowcol<<<544, 256, 0, stream>>>(Drow, Dcol, accum);
    k_angred<<<256, 256, 0, stream>>>(Gb, accum);
    k_fin   <<<1, 64, 0, stream>>>(accum, out);
}

// Round 3
// 181.476 us; speedup vs baseline: 1.6345x; 1.2162x over previous
//
#include <hip/hip_runtime.h>
#include <math.h>

typedef __attribute__((ext_vector_type(8)))  short  short8;
typedef __attribute__((ext_vector_type(16))) float  float16;

#define TWO_PI_OVER_32 0.19634954084936207f

static __device__ __forceinline__ unsigned short f2bf(float f) {
    unsigned int u = __float_as_uint(f);
    u = (u + 0x7FFFu + ((u >> 16) & 1u)) >> 16;
    return (unsigned short)u;
}
static __device__ __forceinline__ float bf2f(unsigned short s) {
    return __uint_as_float(((unsigned int)s) << 16);
}

// async global->LDS 16B: per-lane global src, wave-uniform LDS base + lane*16
static __device__ __forceinline__ void g2l16(const void* g, void* l) {
    __builtin_amdgcn_global_load_lds(
        (const __attribute__((address_space(1))) unsigned int*)g,
        (__attribute__((address_space(3))) unsigned int*)l, 16, 0, 0);
}

// ---------------------------------------------------------------------------
// K_prep: fused weight-side preprocessing.
//  blocks 0..255  (row mode, p=blk): Drow[p][45]; wt bf16 granules; Vb bf16
//  blocks 256..511 (col mode, c=blk-256): Dcol[c][45]
//  block 0 zeroes accum.
// ---------------------------------------------------------------------------
__global__ __launch_bounds__(256) void k_prep(const float* __restrict__ w,
                                              unsigned short* __restrict__ wt,
                                              unsigned short* __restrict__ Vb,
                                              float* __restrict__ Drow,
                                              float* __restrict__ Dcol,
                                              float* __restrict__ accum) {
    __shared__ float sdata[45];
    __shared__ float ws2[256 * 9];
    int blk = blockIdx.x, tid = threadIdx.x, lane = tid & 63;
    bool colmode = blk >= 256;
    int pc = blk & 255;
    if (blk == 0 && tid < 4) accum[tid] = 0.f;
    if (tid < 45) sdata[tid] = 0.f;

    int p = colmode ? tid : pc;
    int c = colmode ? pc : tid;
    float w9[9];
    #pragma unroll
    for (int t = 0; t < 9; ++t) w9[t] = w[(p * 256 + c) * 9 + t];
    if (!colmode) {
        #pragma unroll
        for (int t = 0; t < 9; ++t) ws2[tid * 9 + t] = w9[t];
    }
    __syncthreads();

    int idx = 0;
    for (int ta = 0; ta < 9; ++ta)
        for (int tb = ta; tb < 9; ++tb) {
            float v = w9[ta] * w9[tb];
            #pragma unroll
            for (int off = 32; off > 0; off >>= 1) v += __shfl_down(v, off);
            if (lane == 0) atomicAdd(&sdata[idx], v);
            ++idx;
        }
    __syncthreads();
    if (tid < 45) (colmode ? Dcol : Drow)[pc * 45 + tid] = sdata[tid];

    if (!colmode) {
        // wt granule layout [t][ci>>3][co][ci&7]; this block covers co=p, all ci
        #pragma unroll
        for (int t = 0; t < 9; ++t)
            wt[t * 65536 + (c >> 3) * 2048 + p * 8 + (c & 7)] = f2bf(w9[t]);
        // Vb granules [row=p*10+ta][cig 32][8ci], tap slot 9 zeroed
        if (tid < 320) {
            int ta = tid >> 5, cig = tid & 31;
            union { unsigned short u[8]; uint4 v; } pk;
            #pragma unroll
            for (int u = 0; u < 8; ++u)
                pk.u[u] = (ta < 9) ? f2bf(ws2[(cig * 8 + u) * 9 + ta]) : (unsigned short)0;
            ((uint4*)Vb)[(p * 10 + ta) * 32 + cig] = pk.v;
        }
    }
}

// ---------------------------------------------------------------------------
// K0b: x fp32 (b,ci,r,c) -> xb bf16 granules [b][ci>>3][r][c][ci&7]
// ---------------------------------------------------------------------------
__global__ __launch_bounds__(256) void k_xcvt(const float* __restrict__ x,
                                              unsigned short* __restrict__ xb) {
    int g = blockIdx.x * 256 + threadIdx.x;        // 1,048,576 granules
    int c = g & 31, r = (g >> 5) & 31, cig = (g >> 10) & 31, b = g >> 15;
    const float* xp = x + ((b * 256 + cig * 8) * 32 + r) * 32 + c;
    union { unsigned short u[8]; uint4 v; } pk;
    #pragma unroll
    for (int u = 0; u < 8; ++u) pk.u[u] = f2bf(xp[u * 1024]);
    ((uint4*)xb)[g] = pk.v;
}

// ---------------------------------------------------------------------------
// K1: conv via implicit GEMM. Block = 4 waves sharing co-tile 64; weights
// staged to LDS once per block per kc; all staging via global_load_lds(16B).
// Wave tile: M=64 co x N=64 (2 rows x 32 cols). 512 blocks -> 2 blocks/CU,
// 2 waves/SIMD. XCD-swizzled block id: blocks of one b stay on one XCD.
// ---------------------------------------------------------------------------
__global__ __launch_bounds__(256, 2) void k_conv(const unsigned short* __restrict__ xb,
                                                 const unsigned short* __restrict__ wt,
                                                 const float* __restrict__ bias,
                                                 float* __restrict__ y) {
    __shared__ unsigned short xs[640 * 8];    // [slot 10][cig 2][col 32][8ci] 10240 B
    __shared__ unsigned short wsm[1152 * 8];  // [t 9][cig 2][co 64][8ci]     18432 B

    const int tid  = threadIdx.x;
    const int lane = tid & 63;
    const int wv   = tid >> 6;               // wave 0..3 -> row pair
    const int half = lane >> 5;
    const int m    = lane & 31;

    const int id    = blockIdx.x;
    const int xcd   = id & 7;
    const int local = id >> 3;
    const int b     = xcd * 4 + (local >> 4);
    const int rem   = local & 15;
    const int co0   = (rem & 3) * 64;
    const int r0    = (rem >> 2) * 8;

    float16 acc[2][2];
    #pragma unroll
    for (int i = 0; i < 2; ++i)
        #pragma unroll
        for (int ns = 0; ns < 2; ++ns)
            #pragma unroll
            for (int r = 0; r < 16; ++r) acc[i][ns][r] = 0.f;

    const uint4* xbv = (const uint4*)xb;
    const uint4* wtv = (const uint4*)wt;
    uint4* xsv = (uint4*)xs;
    uint4* wsv = (uint4*)wsm;
    const short8* xsl = (const short8*)xs;
    const short8* wsl = (const short8*)wsm;

    const int cigl = lane >> 5;              // for x staging
    const int coll = lane & 31;

    #pragma unroll 1
    for (int kc = 0; kc < 16; ++kc) {
        // stage x: 10 chunks of 64 granules; chunk ch -> slot ch
        for (int ch = wv; ch < 10; ch += 4) {
            int gr = (r0 + ch + 31) & 31;
            g2l16(&xbv[((b * 32 + kc * 2 + cigl) * 32 + gr) * 32 + coll],
                  &xsv[ch * 64]);
        }
        // stage w: 18 chunks; chunk ch -> t=ch>>1, cig=ch&1, co=lane
        for (int ch = wv; ch < 18; ch += 4) {
            int t = ch >> 1, cig = ch & 1;
            g2l16(&wtv[t * 8192 + (kc * 2 + cig) * 256 + co0 + lane],
                  &wsv[ch * 64]);
        }
        __syncthreads();

        #pragma unroll
        for (int t = 0; t < 9; ++t) {
            const int atv = t / 3, btv = t % 3;
            short8 a0 = wsl[(t * 2 + half) * 64 + m];
            short8 a1 = wsl[(t * 2 + half) * 64 + 32 + m];
            #pragma unroll
            for (int ns = 0; ns < 2; ++ns) {
                int slot = wv * 2 + ns + atv;          // 0..9
                short8 bf = xsl[(slot * 2 + half) * 32 + ((m + btv + 31) & 31)];
                acc[0][ns] = __builtin_amdgcn_mfma_f32_32x32x16_bf16(a0, bf, acc[0][ns], 0, 0, 0);
                acc[1][ns] = __builtin_amdgcn_mfma_f32_32x32x16_bf16(a1, bf, acc[1][ns], 0, 0, 0);
            }
        }
        __syncthreads();
    }

    // epilogue: C layout: col=lane&31, row=(reg&3)+8*(reg>>2)+4*half
    #pragma unroll
    for (int i = 0; i < 2; ++i) {
        #pragma unroll
        for (int ns = 0; ns < 2; ++ns) {
            int r = r0 + wv * 2 + ns;
            #pragma unroll
            for (int reg = 0; reg < 16; ++reg) {
                int crow = (reg & 3) + 8 * (reg >> 2) + 4 * half;
                int co = co0 + i * 32 + crow;
                y[(b * 256 + co) * 1024 + r * 32 + m] = acc[i][ns][reg] + bias[co];
            }
        }
    }
}

// ---------------------------------------------------------------------------
// K3: Row/Col loss accumulation per bin
// ---------------------------------------------------------------------------
__global__ __launch_bounds__(256) void k_rowcol(const float* __restrict__ Drow,
                                                const float* __restrict__ Dcol,
                                                float* __restrict__ accum) {
    int bin = blockIdx.x;          // 0..543
    int u = bin / 17, v = bin % 17;
    __shared__ float coef[45];
    __shared__ float red[2];
    int tid = threadIdx.x;
    if (tid < 2) red[tid] = 0.f;
    if (tid < 45) {
        int idx = 0, TA = 0, TB = 0;
        for (int ta = 0; ta < 9; ++ta)
            for (int tb = ta; tb < 9; ++tb) {
                if (idx == tid) { TA = ta; TB = tb; }
                ++idx;
            }
        int da = TA / 3 - TB / 3;
        int db = TA % 3 - TB % 3;
        float cth = cosf(TWO_PI_OVER_32 * (float)(u * da + v * db));
        coef[tid] = (TA == TB) ? 1.f : 2.f * cth;
    }
    __syncthreads();

    float s1 = 0.f, s2 = 0.f;
    const float* dr = Drow + tid * 45;
    const float* dc = Dcol + tid * 45;
    #pragma unroll
    for (int i = 0; i < 45; ++i) {
        s1 += coef[i] * dr[i];
        s2 += coef[i] * dc[i];
    }
    float e1 = sqrtf(fmaxf(s1, 0.f)) - 1.f; e1 *= e1;
    float e2 = sqrtf(fmaxf(s2, 0.f)) - 1.f; e2 *= e2;
    #pragma unroll
    for (int off = 32; off > 0; off >>= 1) {
        e1 += __shfl_down(e1, off);
        e2 += __shfl_down(e2, off);
    }
    if ((tid & 63) == 0) { atomicAdd(&red[0], e1); atomicAdd(&red[1], e2); }
    __syncthreads();
    if (tid == 0) { atomicAdd(&accum[0], red[0]); atomicAdd(&accum[1], red[1]); }
}

// ---------------------------------------------------------------------------
// K4b: Gram G = V V^T (2560x2560, K=256) bf16 MFMA, upper-triangle tiles only.
// ---------------------------------------------------------------------------
__global__ __launch_bounds__(256) void k_gram(const unsigned short* __restrict__ Vb,
                                              unsigned short* __restrict__ Gb) {
    int blk = blockIdx.x, I = 0;
    while (blk >= 20 - I) { blk -= 20 - I; ++I; }
    int J = I + blk;

    const int tid  = threadIdx.x;
    const int lane = tid & 63;
    const int wave = tid >> 6;
    const int wm = wave >> 1, wn = wave & 1;
    const int half = lane >> 5;
    const int m = lane & 31;

    const int row0 = I * 128 + wm * 64;
    const int col0 = J * 128 + wn * 64;

    float16 acc[2][2];
    #pragma unroll
    for (int i = 0; i < 2; ++i)
        #pragma unroll
        for (int j = 0; j < 2; ++j)
            #pragma unroll
            for (int r = 0; r < 16; ++r) acc[i][j][r] = 0.f;

    const short8* vb = (const short8*)Vb;
    for (int kc = 0; kc < 16; ++kc) {
        int cig = kc * 2 + half;
        short8 a0 = vb[(row0 + m) * 32 + cig];
        short8 a1 = vb[(row0 + 32 + m) * 32 + cig];
        short8 b0 = vb[(col0 + m) * 32 + cig];
        short8 b1 = vb[(col0 + 32 + m) * 32 + cig];
        acc[0][0] = __builtin_amdgcn_mfma_f32_32x32x16_bf16(a0, b0, acc[0][0], 0, 0, 0);
        acc[0][1] = __builtin_amdgcn_mfma_f32_32x32x16_bf16(a0, b1, acc[0][1], 0, 0, 0);
        acc[1][0] = __builtin_amdgcn_mfma_f32_32x32x16_bf16(a1, b0, acc[1][0], 0, 0, 0);
        acc[1][1] = __builtin_amdgcn_mfma_f32_32x32x16_bf16(a1, b1, acc[1][1], 0, 0, 0);
    }
    #pragma unroll
    for (int i = 0; i < 2; ++i)
        #pragma unroll
        for (int j = 0; j < 2; ++j)
            #pragma unroll
            for (int reg = 0; reg < 16; ++reg) {
                int crow = (reg & 3) + 8 * (reg >> 2) + 4 * half;
                Gb[(row0 + i * 32 + crow) * 2560 + col0 + j * 32 + m] =
                    f2bf(acc[i][j][reg]);
            }
}

// ---------------------------------------------------------------------------
// K4c: AngLoss reduction (closed-form over bins via delta-grouped g[5][5])
// ---------------------------------------------------------------------------
__global__ __launch_bounds__(256) void k_angred(const unsigned short* __restrict__ Gb,
                                                float* __restrict__ accum) {
    int p = blockIdx.x;
    __shared__ unsigned short gs[9 * 2560];    // 46080 B
    __shared__ float red;
    if (threadIdx.x == 0) red = 0.f;
    uint4* gsv = (uint4*)gs;
    const uint4* gbv = (const uint4*)Gb;
    for (int i = threadIdx.x; i < 2880; i += 256) {
        int rr = i / 320, cc = i - rr * 320;
        gsv[i] = gbv[(p * 10 + rr) * 320 + cc];
    }
    __syncthreads();

    int q = threadIdx.x;
    float S = 0.f;
    if (q > p) {
        float g5[5][5];
        #pragma unroll
        for (int i = 0; i < 5; ++i)
            #pragma unroll
            for (int j = 0; j < 5; ++j) g5[i][j] = 0.f;
        #pragma unroll
        for (int ta = 0; ta < 9; ++ta)
            #pragma unroll
            for (int tb = 0; tb < 9; ++tb) {
                float c = bf2f(gs[ta * 2560 + q * 10 + tb]);
                g5[ta / 3 - tb / 3 + 2][ta % 3 - tb % 3 + 2] += c;
            }
        float ReS[5];
        #pragma unroll
        for (int d = 0; d < 5; ++d) {
            float s = 0.f;
            for (int vv = 0; vv < 17; ++vv)
                s += cosf(TWO_PI_OVER_32 * (float)(vv * d));
            ReS[d] = s;
        }
        #pragma unroll
        for (int da = 0; da < 5; ++da)
            #pragma unroll
            for (int d1 = 0; d1 < 5; ++d1)
                #pragma unroll
                for (int d2 = 0; d2 < 5; ++d2) {
                    int dd = d1 - d2; if (dd < 0) dd = -dd;
                    S += g5[da][d1] * g5[da][d2] * ReS[dd];
                }
        S *= 32.f;
    }
    #pragma unroll
    for (int off = 32; off > 0; off >>= 1) S += __shfl_down(S, off);
    if ((threadIdx.x & 63) == 0) atomicAdd(&red, S);
    __syncthreads();
    if (threadIdx.x == 0) atomicAdd(&accum[2], red);
}

// ---------------------------------------------------------------------------
// K5: finalize L
// ---------------------------------------------------------------------------
__global__ void k_fin(const float* __restrict__ accum, float* __restrict__ out) {
    if (threadIdx.x == 0 && blockIdx.x == 0) {
        float row = accum[0], col = accum[1], ang = accum[2];
        out[8388608] = row / 544.f + col / 544.f + ang / (544.f * 32640.f);
    }
}

// ---------------------------------------------------------------------------
extern "C" void kernel_launch(void* const* d_in, const int* in_sizes, int n_in,
                              void* d_out, int out_size, void* d_ws, size_t ws_size,
                              hipStream_t stream) {
    const float* x    = (const float*)d_in[0];   // (32,256,32,32)
    const float* w    = (const float*)d_in[1];   // (256,256,3,3)
    const float* bias = (const float*)d_in[2];   // (256,)
    float* out = (float*)d_out;

    char* ws = (char*)d_ws;
    unsigned short* wt = (unsigned short*)ws;               //  1,179,648 B
    unsigned short* xb = (unsigned short*)(ws + 1179648);   // 16,777,216 B
    unsigned short* Gb = xb;                                // aliases xb (after conv)
    unsigned short* Vb = (unsigned short*)(ws + 17956864);  //  1,310,720 B
    float* Drow  = (float*)(ws + 19267584);                 //     46,080 B
    float* Dcol  = (float*)(ws + 19313664);                 //     46,080 B
    float* accum = (float*)(ws + 19359744);                 //         16 B

    k_prep  <<<512, 256, 0, stream>>>(w, wt, Vb, Drow, Dcol, accum);
    k_xcvt  <<<4096, 256, 0, stream>>>(x, xb);
    k_conv  <<<512, 256, 0, stream>>>(xb, wt, bias, out);
    k_gram  <<<210, 256, 0, stream>>>(Vb, Gb);              // Gb overwrites xb region
    k_rowcol<<<544, 256, 0, stream>>>(Drow, Dcol, accum);
    k_angred<<<256, 256, 0, stream>>>(Gb, accum);
    k_fin   <<<1, 64, 0, stream>>>(accum, out);
}